// Round 5
// baseline (759.635 us; speedup 1.0000x reference)
//
#include <hip/hip_runtime.h>
#include <math.h>

// ---------------- constants ----------------
#define T99   99
#define CC    256
#define NHH   8
#define FEAT  400
#define NS_   32
#define LSTEP 33

typedef __attribute__((ext_vector_type(8))) short s8v;   // 8 x bf16 (as raw u16)
typedef __attribute__((ext_vector_type(4))) float f4v;   // MFMA accumulator

__device__ __forceinline__ void mfma_bf16(f4v& d, s8v a, s8v b) {
  asm volatile("v_mfma_f32_16x16x32_bf16 %0, %1, %2, %0" : "+v"(d) : "v"(a), "v"(b));
}

__device__ __forceinline__ unsigned short f2bf(float f) {
  union { float f; unsigned u; } x; x.f = f;
  unsigned r = x.u + 0x7FFFu + ((x.u >> 16) & 1u);
  return (unsigned short)(r >> 16);
}
__device__ __forceinline__ float bf2f(unsigned short h) {
  union { unsigned u; float f; } x; x.u = ((unsigned)h) << 16;
  return x.f;
}
__device__ __forceinline__ float blo(unsigned u) { union { unsigned x; float f; } c; c.x = u << 16; return c.f; }
__device__ __forceinline__ float bhi(unsigned u) { union { unsigned x; float f; } c; c.x = u & 0xffff0000u; return c.f; }

// sin/cos positional embedding, matches pos_ebb()
__device__ __forceinline__ float pe_val(int pos, int c) {
  int i = c >> 1;
  float freq = expf((float)(2 * i) * (-0.03597789207803197f)); // -ln(10000)/256
  float ang = (float)pos * freq;
  return (c & 1) ? cosf(ang) : sinf(ang);
}

// ---------------- conv stem: grouped conv1d(400->256, k=3, pad=1, g=4) + relu ----------------
__global__ __launch_bounds__(128) void k_convbase(const float* __restrict__ x,
                                                  const float* __restrict__ w,
                                                  const float* __restrict__ bias,
                                                  float* __restrict__ base) {
  int b = blockIdx.x >> 8, co = blockIdx.x & 255, t = threadIdx.x;
  if (t >= T99) return;
  int g = co >> 6;
  float acc = bias[co];
  const float* xp = x + (size_t)(b * FEAT + g * 100) * T99;
  const float* wp = w + (size_t)co * 300;
  for (int ic = 0; ic < 100; ++ic) {
    float x0 = (t > 0)  ? xp[ic * T99 + t - 1] : 0.f;
    float x1 = xp[ic * T99 + t];
    float x2 = (t < 98) ? xp[ic * T99 + t + 1] : 0.f;
    acc += wp[ic * 3] * x0 + wp[ic * 3 + 1] * x1 + wp[ic * 3 + 2] * x2;
  }
  base[(size_t)(b * CC + co) * T99 + t] = fmaxf(acc, 0.f);
}

// ---------------- weight conversion: pack {qkv,o,l1,l2} per layer into bf16 ----------------
__global__ __launch_bounds__(256) void k_convW(const float* __restrict__ qkv, const float* __restrict__ o,
                                               const float* __restrict__ l1, const float* __restrict__ l2,
                                               int L, unsigned short* __restrict__ dst) {
  int total = L * 786432;
  for (int idx = blockIdx.x * 256 + threadIdx.x; idx < total; idx += gridDim.x * 256) {
    int l = idx / 786432, r = idx % 786432;
    float v;
    if (r < 196608)      v = qkv[(size_t)l * 196608 + r];
    else if (r < 262144) v = o[(size_t)l * 65536 + (r - 196608)];
    else if (r < 524288) v = l1[(size_t)l * 262144 + (r - 262144)];
    else                 v = l2[(size_t)l * 262144 + (r - 524288)];
    dst[idx] = f2bf(v);
  }
}

// ---------------- build encoder inputs (fp32 stream + bf16 mirror) ----------------
__global__ __launch_bounds__(256) void k_build_xg(const float* __restrict__ base, float* __restrict__ xg,
                                                  unsigned short* __restrict__ xgb) {
  int idx = blockIdx.x * 256 + threadIdx.x;
  int t = idx >> 10, r = idx & 1023, b4 = r >> 8, c = r & 255;
  float v = (b4 < 2) ? base[(size_t)(b4 * CC + c) * T99 + t]
                     : base[(size_t)((b4 - 2) * CC + c) * T99 + (98 - t)];
  v += pe_val(t, c);
  xg[idx] = v; xgb[idx] = f2bf(v);
}

__global__ __launch_bounds__(256) void k_build_xl(const float* __restrict__ base, float* __restrict__ xl,
                                                  unsigned short* __restrict__ xlb) {
  int idx = blockIdx.x * 256 + threadIdx.x;
  int ls = idx / 1536, r = idx % 1536, j = r >> 8, c = r & 255;
  int g = j >> 1, b = j & 1, t = ls * 3 + g;
  float v = base[(size_t)(b * CC + c) * T99 + t] + pe_val(ls, c);
  xl[idx] = v; xlb[idx] = f2bf(v);
}

// ================= GEMM core (64x64 tile, bf16 MFMA) =================
// flags: 1=relu, 2=residual R, 4=write bf16 Yb, 8=skip fp32 Y
__device__ __forceinline__ void gemm_body(const unsigned short* __restrict__ A,
                                          const unsigned short* __restrict__ W,
                                          const float* __restrict__ bias,
                                          const float* __restrict__ R,
                                          float* __restrict__ Y,
                                          unsigned short* __restrict__ Yb,
                                          int M, int N, int K, int flags,
                                          int m0, int n0) {
  __shared__ __align__(16) unsigned short Al[64][40];
  __shared__ __align__(16) unsigned short Bl[64][40];
  int tid = threadIdx.x;
  int lane = tid & 63, w = tid >> 6, wm = w >> 1, wn = w & 1;
  int sp = tid >> 2, kc = (tid & 3) << 3;
  f4v zero4 = {0.f, 0.f, 0.f, 0.f};
  f4v acc[2][2];
#pragma unroll
  for (int mt = 0; mt < 2; ++mt)
#pragma unroll
    for (int nt = 0; nt < 2; ++nt) acc[mt][nt] = zero4;

  for (int k0 = 0; k0 < K; k0 += 32) {
    s8v av = {0, 0, 0, 0, 0, 0, 0, 0};
    int row = m0 + sp;
    if (row < M) av = *(const s8v*)&A[(size_t)row * K + k0 + kc];
    *(s8v*)&Al[sp][kc] = av;
    *(s8v*)&Bl[sp][kc] = *(const s8v*)&W[(size_t)(n0 + sp) * K + k0 + kc];
    __syncthreads();
    s8v af[2], bf[2];
#pragma unroll
    for (int mt = 0; mt < 2; ++mt)
      af[mt] = *(const s8v*)&Al[wm * 32 + mt * 16 + (lane & 15)][(lane >> 4) * 8];
#pragma unroll
    for (int nt = 0; nt < 2; ++nt)
      bf[nt] = *(const s8v*)&Bl[wn * 32 + nt * 16 + (lane & 15)][(lane >> 4) * 8];
#pragma unroll
    for (int mt = 0; mt < 2; ++mt)
#pragma unroll
      for (int nt = 0; nt < 2; ++nt) mfma_bf16(acc[mt][nt], af[mt], bf[nt]);
    __syncthreads();
  }
  asm volatile("s_nop 7\n\ts_nop 7\n\ts_nop 4");
#pragma unroll
  for (int mt = 0; mt < 2; ++mt) {
#pragma unroll
    for (int nt = 0; nt < 2; ++nt) {
      int col = n0 + wn * 32 + nt * 16 + (lane & 15);
      float bv = bias[col];
#pragma unroll
      for (int r = 0; r < 2 * 2; ++r) {
        int row = m0 + wm * 32 + mt * 16 + (lane >> 4) * 4 + r;
        if (row < M) {
          float v = acc[mt][nt][r] + bv;
          if (flags & 2) v += R[(size_t)row * N + col];
          if (flags & 1) v = fmaxf(v, 0.f);
          if (!(flags & 8)) Y[(size_t)row * N + col] = v;
          if (flags & 4) Yb[(size_t)row * N + col] = f2bf(v);
        }
      }
    }
  }
}

__global__ __launch_bounds__(256) void k_gemmb(const unsigned short* __restrict__ A,
                                               const unsigned short* __restrict__ W,
                                               const float* __restrict__ bias,
                                               const float* __restrict__ R,
                                               float* __restrict__ Y,
                                               unsigned short* __restrict__ Yb,
                                               int M, int N, int K, int flags) {
  gemm_body(A, W, bias, R, Y, Yb, M, N, K, flags, blockIdx.x * 64, blockIdx.y * 64);
}

// dual-job GEMM: z=0 -> job L (local), z=1 -> job G (global). Same N,K,flags.
__global__ __launch_bounds__(256) void k_gemmb2(const unsigned short* __restrict__ A0,
                                                const unsigned short* __restrict__ W0,
                                                const float* __restrict__ bias0,
                                                const float* __restrict__ R0,
                                                float* __restrict__ Y0,
                                                unsigned short* __restrict__ Yb0,
                                                int M0,
                                                const unsigned short* __restrict__ A1,
                                                const unsigned short* __restrict__ W1,
                                                const float* __restrict__ bias1,
                                                const float* __restrict__ R1,
                                                float* __restrict__ Y1,
                                                unsigned short* __restrict__ Yb1,
                                                int M1,
                                                int N, int K, int flags) {
  int m0 = blockIdx.x * 64;
  if (blockIdx.z == 0) {
    if (m0 >= M0) return;
    gemm_body(A0, W0, bias0, R0, Y0, Yb0, M0, N, K, flags, m0, blockIdx.y * 64);
  } else {
    if (m0 >= M1) return;
    gemm_body(A1, W1, bias1, R1, Y1, Yb1, M1, N, K, flags, m0, blockIdx.y * 64);
  }
}

// ---------------- attention: one block per (b,h,q); bf16 in, fp32 math, bf16 out ----------------
__device__ __forceinline__ void attn_body(const unsigned short* __restrict__ qkv,
                                          unsigned short* __restrict__ attb,
                                          int T_, int B_, int bid) {
  __shared__ float qv[32];
  __shared__ float red[128];
  __shared__ float pv[128];
  int tid = threadIdx.x;
  int q = bid % T_;
  int h = (bid / T_) % NHH;
  int b = bid / (T_ * NHH);
  if (tid < 32) qv[tid] = bf2f(qkv[(size_t)(q * B_ + b) * 768 + h * 32 + tid]);
  __syncthreads();
  float s = -1e30f;
  if (tid < T_) {
    const unsigned short* kp = qkv + (size_t)(tid * B_ + b) * 768 + 256 + h * 32;
    float d = 0;
#pragma unroll
    for (int i = 0; i < 32; ++i) d += qv[i] * bf2f(kp[i]);
    s = d * 0.176776695296636881f; // 1/sqrt(32)
  }
  red[tid] = s; __syncthreads();
  for (int o = 64; o > 0; o >>= 1) { if (tid < o) red[tid] = fmaxf(red[tid], red[tid + o]); __syncthreads(); }
  float mx = red[0]; __syncthreads();
  float p = (tid < T_) ? expf(s - mx) : 0.f;
  pv[tid] = p; red[tid] = p; __syncthreads();
  for (int o = 64; o > 0; o >>= 1) { if (tid < o) red[tid] += red[tid + o]; __syncthreads(); }
  float denom = red[0];
  if (tid < 32) {
    float o = 0;
    for (int k = 0; k < T_; ++k) o += pv[k] * bf2f(qkv[(size_t)(k * B_ + b) * 768 + 512 + h * 32 + tid]);
    attb[(size_t)(q * B_ + b) * 256 + h * 32 + tid] = f2bf(o / denom);
  }
}

__global__ __launch_bounds__(128) void k_attn(const unsigned short* __restrict__ qkv,
                                              unsigned short* __restrict__ attb,
                                              int T_, int B_) {
  attn_body(qkv, attb, T_, B_, blockIdx.x);
}

__global__ __launch_bounds__(128) void k_attn2(const unsigned short* __restrict__ qkv0,
                                               unsigned short* __restrict__ attb0, int T0, int B0,
                                               const unsigned short* __restrict__ qkv1,
                                               unsigned short* __restrict__ attb1, int T1, int B1) {
  int bid = blockIdx.x;
  if (blockIdx.z == 0) {
    if (bid >= B0 * NHH * T0) return;
    attn_body(qkv0, attb0, T0, B0, bid);
  } else {
    if (bid >= B1 * NHH * T1) return;
    attn_body(qkv1, attb1, T1, B1, bid);
  }
}

// ---------------- layer norm over C=256; fp32 out + optional bf16 mirror ----------------
__device__ __forceinline__ void ln_body(const float* __restrict__ X, const float* __restrict__ g,
                                        const float* __restrict__ bb, float* __restrict__ Y,
                                        unsigned short* __restrict__ Yb, int tok) {
  __shared__ float rs[256], rq[256];
  int c = threadIdx.x;
  float v = X[(size_t)tok * 256 + c];
  rs[c] = v; rq[c] = v * v; __syncthreads();
  for (int o = 128; o > 0; o >>= 1) { if (c < o) { rs[c] += rs[c + o]; rq[c] += rq[c + o]; } __syncthreads(); }
  float mu = rs[0] * (1.f / 256.f);
  float var = rq[0] * (1.f / 256.f) - mu * mu;
  float r = (v - mu) * rsqrtf(var + 1e-5f) * g[c] + bb[c];
  Y[(size_t)tok * 256 + c] = r;
  if (Yb) Yb[(size_t)tok * 256 + c] = f2bf(r);
}

__global__ __launch_bounds__(256) void k_ln(const float* __restrict__ X, const float* __restrict__ g,
                                            const float* __restrict__ bb, float* __restrict__ Y,
                                            unsigned short* __restrict__ Yb) {
  ln_body(X, g, bb, Y, Yb, blockIdx.x);
}

__global__ __launch_bounds__(256) void k_ln2(const float* __restrict__ X0, const float* __restrict__ g0,
                                             const float* __restrict__ bb0, float* __restrict__ Y0,
                                             unsigned short* __restrict__ Yb0, int n0,
                                             const float* __restrict__ X1, const float* __restrict__ g1,
                                             const float* __restrict__ bb1, float* __restrict__ Y1,
                                             unsigned short* __restrict__ Yb1, int n1) {
  int tok = blockIdx.x;
  if (blockIdx.z == 0) {
    if (tok >= n0) return;
    ln_body(X0, g0, bb0, Y0, Yb0, tok);
  } else {
    if (tok >= n1) return;
    ln_body(X1, g1, bb1, Y1, Yb1, tok);
  }
}

// ---------------- combine: base2 = local + f1 + flip(f2) ----------------
__global__ __launch_bounds__(256) void k_combine(const float* __restrict__ encl, const float* __restrict__ encg,
                                                 float* __restrict__ base2) {
  int idx = blockIdx.x * 256 + threadIdx.x;
  int t = idx % T99, c = (idx / T99) & 255, b = idx / (CC * T99);
  int ls = t / 3, g = t % 3;
  float v = encl[(size_t)(ls * 6 + g * 2 + b) * 256 + c]
          + encg[(size_t)(t * 4 + b) * 256 + c]
          + encg[(size_t)((98 - t) * 4 + 2 + b) * 256 + c];
  base2[idx] = v;
}

// ---------------- s-branch ----------------
__global__ __launch_bounds__(128) void k_s1(const float* __restrict__ base2, const float* __restrict__ w,
                                            const float* __restrict__ bias, float* __restrict__ sbuf) {
  int b = blockIdx.x >> 8, co = blockIdx.x & 255, t = threadIdx.x;
  if (t >= T99) return;
  int g = co >> 6;
  float acc = bias[co];
  const float* xp = base2 + (size_t)(b * CC + g * 64) * T99;
  const float* wp = w + (size_t)co * 192;
  for (int ic = 0; ic < 64; ++ic) {
    float x0 = (t > 0)  ? xp[ic * T99 + t - 1] : 0.f;
    float x1 = xp[ic * T99 + t];
    float x2 = (t < 98) ? xp[ic * T99 + t + 1] : 0.f;
    acc += wp[ic * 3] * x0 + wp[ic * 3 + 1] * x1 + wp[ic * 3 + 2] * x2;
  }
  sbuf[(size_t)(b * CC + co) * T99 + t] = fmaxf(acc, 0.f);
}

__global__ __launch_bounds__(256) void k_s2(const float* __restrict__ sbuf, const float* __restrict__ w,
                                            const float* __restrict__ bias, float* __restrict__ out) {
  __shared__ float rs[256];
  int b = blockIdx.x / T99, t = blockIdx.x % T99, c = threadIdx.x;
  rs[c] = w[c] * sbuf[(size_t)(b * CC + c) * T99 + t];
  __syncthreads();
  for (int o = 128; o > 0; o >>= 1) { if (c < o) rs[c] += rs[c + o]; __syncthreads(); }
  if (c == 0) out[blockIdx.x] = 1.f / (1.f + expf(-(rs[0] + bias[0])));
}

// ---------------- w3 transpose: w3t[n][ci][co] = c3_w[co][ci][n] ----------------
__global__ __launch_bounds__(256) void k_w3t(const float* __restrict__ c3w, float* __restrict__ w3t) {
  int idx = blockIdx.x * 256 + threadIdx.x;
  int co = idx & 255, ci = (idx >> 8) & 255, n = idx >> 16;
  w3t[idx] = c3w[((size_t)(co << 8) + ci) * 32 + n];
}

// ---------------- Gb[n][t][co][b] (bf16, b-interleaved) + zero pad row ----------------
__global__ __launch_bounds__(256) void k_G(const float* __restrict__ w3t, const float* __restrict__ base2,
                                           unsigned short* __restrict__ Gb) {
  int tc = blockIdx.x, n = blockIdx.y, b = blockIdx.z;
  int co = threadIdx.x;
  int t0 = tc * 25;
  float acc[25];
#pragma unroll
  for (int q = 0; q < 25; ++q) acc[q] = 0.f;
  const float* w = w3t + (size_t)n * 65536 + co;
  const float* bs = base2 + (size_t)b * CC * T99 + t0;
  for (int ci = 0; ci < 256; ++ci) {
    float wv = w[(size_t)ci * 256];
#pragma unroll
    for (int q = 0; q < 25; ++q) acc[q] += wv * bs[ci * T99 + q];
  }
#pragma unroll
  for (int q = 0; q < 25; ++q) {
    int t = t0 + q;
    if (t < T99) Gb[((size_t)(n * T99 + t) * 256 + co) * 2 + b] = f2bf(acc[q]);
  }
  // zero the 1-row pad (read by k_ppre's +1024B load with weight 0)
  if (tc == 0 && n == 0 && b == 0)
    ((unsigned int*)(Gb + (size_t)NS_ * T99 * 512))[co] = 0u;
}

// ---------------- p_pre: fused bm-gather + conv3d + relu -> bf16 channel-last ----------------
__global__ __launch_bounds__(128) void k_ppre(const unsigned short* __restrict__ Gb,
                                              const float* __restrict__ c3b,
                                              unsigned int* __restrict__ pinb32) {
  __shared__ float w0s[96], w1s[96];
  __shared__ int   ofs[96];
  int e = blockIdx.x % T99, s = blockIdx.x / T99;
  int tid = threadIdx.x;
  if (s >= e) {
    float z0 = fmaxf(c3b[2 * tid], 0.f), z1 = fmaxf(c3b[2 * tid + 1], 0.f);
    unsigned int zz = ((unsigned)f2bf(z1) << 16) | (unsigned)f2bf(z0);
    pinb32[((size_t)(0 * T99 + s) * T99 + e) * 128 + tid] = zz;
    pinb32[((size_t)(1 * T99 + s) * T99 + e) * 128 + tid] = zz;
    return;
  }
  if (tid < 96) {
    double center = (double)(e - s + 1);
    double S = ((double)s - 0.5 * center) + ((2.0 * center - 1.0) / 95.0) * (double)tid;
    double dn = trunc(S);
    double dec = S - dn;
    int di = (int)dn;
    double uc = ceil(S);
    int ui = (int)uc;
    int n = tid / 3;
    float w0 = 0.f, w1 = 0.f;
    int r0 = 0;
    if (dn >= 0.0 && dn <= 98.0) {
      r0 = di;
      w0 = (float)((1.0 - dec) / 3.0);
      if (uc >= 0.0 && uc <= 98.0) {
        if (ui == di) w0 += (float)(dec / 3.0);
        else          w1  = (float)(dec / 3.0);   // ui == di+1 guaranteed here
      }
    }
    w0s[tid] = w0; w1s[tid] = w1;
    ofs[tid] = (n * T99 + r0) * 1024;  // byte offset of row r0 (256 uints/row)
  }
  __syncthreads();
  float a00 = 0.f, a01 = 0.f, a10 = 0.f, a11 = 0.f; // a[co-sub][b]
  const char* basep = (const char*)Gb + tid * 8;
#pragma unroll 8
  for (int k = 0; k < 96; ++k) {
    float w0 = w0s[k], w1 = w1s[k];
    const uint2* p = (const uint2*)(basep + ofs[k]);
    uint2 u0 = p[0];
    uint2 u1 = p[128];  // +1024 bytes = row r0+1
    a00 += w0 * blo(u0.x) + w1 * blo(u1.x);
    a01 += w0 * bhi(u0.x) + w1 * bhi(u1.x);
    a10 += w0 * blo(u0.y) + w1 * blo(u1.y);
    a11 += w0 * bhi(u0.y) + w1 * bhi(u1.y);
  }
  float b0 = c3b[2 * tid], b1 = c3b[2 * tid + 1];
  unsigned int zb0 = ((unsigned)f2bf(fmaxf(a10 + b1, 0.f)) << 16) | (unsigned)f2bf(fmaxf(a00 + b0, 0.f));
  unsigned int zb1 = ((unsigned)f2bf(fmaxf(a11 + b1, 0.f)) << 16) | (unsigned)f2bf(fmaxf(a01 + b0, 0.f));
  pinb32[((size_t)(0 * T99 + s) * T99 + e) * 128 + tid] = zb0;
  pinb32[((size_t)(1 * T99 + s) * T99 + e) * 128 + tid] = zb1;
}

// ---------------- weight pack for conv3x3: frag-order layout ----------------
// wbf chunk = (tap*8 + kst)*16 + cog; each chunk = 512 halfs = lane*8 (lane: co=cog*16+(lane&15), k=kst*32+(lane>>4)*8)
// src pw[co][ci][tap] (3x3 -> tap = kh*3+kw)
__global__ __launch_bounds__(256) void k_wb2(const float* __restrict__ pw, unsigned short* __restrict__ wbf) {
  int idx = blockIdx.x * 256 + threadIdx.x;   // 0 .. 73727
  if (idx >= 73728) return;
  int lane = idx & 63;
  int cog  = (idx >> 6) & 15;
  int kst  = (idx >> 10) & 7;
  int tap  = idx >> 13;
  int co = cog * 16 + (lane & 15);
  int k  = kst * 32 + (lane >> 4) * 8;
  s8v v;
#pragma unroll
  for (int j = 0; j < 8; ++j)
    v[j] = (short)f2bf(pw[((size_t)co * 256 + k + j) * 9 + tap]);
  *(s8v*)&wbf[(size_t)idx * 8] = v;
}

// ---------------- 3x3 conv (256->256, pad=1): halo-LDS + barrier-free MFMA main loop ----------------
// block: 8x8 spatial tile, 128 co, one b. 4 waves (2 sp x 2 co), wave = 32sp x 64co.
__global__ __launch_bounds__(256) void k_conv3x3(const unsigned short* __restrict__ in,
                                                 const unsigned short* __restrict__ wbf,
                                                 const float* __restrict__ bias,
                                                 unsigned short* __restrict__ out) {
  __shared__ __align__(16) unsigned short Ah[100 * 264];  // 10x10 halo rows, padded stride 264
  int b = blockIdx.z;
  int co0 = blockIdx.y * 128;
  int ti = blockIdx.x / 13, tj = blockIdx.x % 13;
  int i0 = ti * 8, j0 = tj * 8;
  int tid = threadIdx.x;
  // stage halo once: 100 rows x 256 ch
#pragma unroll
  for (int it = 0; it < 13; ++it) {
    int chunk = it * 256 + tid;
    if (chunk < 3200) {
      int row = chunk >> 5;
      int cc = (chunk & 31) * 8;
      int gi = i0 + row / 10 - 1, gj = j0 + row % 10 - 1;
      s8v val = {0, 0, 0, 0, 0, 0, 0, 0};
      if (gi >= 0 && gi < T99 && gj >= 0 && gj < T99)
        val = *(const s8v*)&in[((size_t)(b * T99 + gi) * T99 + gj) * 256 + cc];
      *(s8v*)&Ah[row * 264 + cc] = val;
    }
  }
  __syncthreads();

  int lane = tid & 63, w = tid >> 6, wm = w >> 1, wn = w & 1;
  int l15 = lane & 15, lk = lane >> 4;
  int spL0 = wm * 32 + l15;
  int spL1 = spL0 + 16;
  int hr0 = (spL0 >> 3) * 10 + (spL0 & 7) + 11;
  int hr1 = (spL1 >> 3) * 10 + (spL1 & 7) + 11;
  int cogbase = blockIdx.y * 8 + wn * 4;

  f4v acc[2][4];
#pragma unroll
  for (int mt = 0; mt < 2; ++mt)
#pragma unroll
    for (int nt = 0; nt < 4; ++nt) acc[mt][nt] = (f4v){0.f, 0.f, 0.f, 0.f};

  for (int tap = 0; tap < 9; ++tap) {
    int doff = (tap / 3) * 10 + (tap % 3) - 11;
    const unsigned short* bbase = wbf + ((size_t)(tap * 8) * 16) * 512 + (size_t)lane * 8;
#pragma unroll
    for (int kst = 0; kst < 8; ++kst) {
      int k0 = kst * 32;
      s8v a0 = *(const s8v*)&Ah[(hr0 + doff) * 264 + k0 + lk * 8];
      s8v a1 = *(const s8v*)&Ah[(hr1 + doff) * 264 + k0 + lk * 8];
      const unsigned short* bp = bbase + ((size_t)(kst * 16 + cogbase)) * 512;
#pragma unroll
      for (int nt = 0; nt < 4; ++nt) {
        s8v bf = *(const s8v*)&bp[(size_t)nt * 512];
        mfma_bf16(acc[0][nt], a0, bf);
        mfma_bf16(acc[1][nt], a1, bf);
      }
    }
  }
  asm volatile("s_nop 7\n\ts_nop 7\n\ts_nop 4");
#pragma unroll
  for (int mt = 0; mt < 2; ++mt) {
#pragma unroll
    for (int nt = 0; nt < 4; ++nt) {
      int co = co0 + wn * 64 + nt * 16 + l15;
      float bv = bias[co];
#pragma unroll
      for (int r = 0; r < 4; ++r) {
        int sp = wm * 32 + mt * 16 + lk * 4 + r;
        int gi = i0 + (sp >> 3), gj = j0 + (sp & 7);
        if (gi < T99 && gj < T99) {
          float v = fmaxf(acc[mt][nt][r] + bv, 0.f);
          out[((size_t)(b * T99 + gi) * T99 + gj) * 256 + co] = f2bf(v);
        }
      }
    }
  }
}

// ---------------- p3 1x1 conv (256->2) + sigmoid -> cm ----------------
__global__ __launch_bounds__(256) void k_p3(const unsigned short* __restrict__ p2o,
                                            const float* __restrict__ w, const float* __restrict__ bias,
                                            float* __restrict__ cm) {
  int idx = blockIdx.x * 256 + threadIdx.x;
  if (idx >= 2 * 2 * T99 * T99) return;
  int j = idx % T99, i = (idx / T99) % T99, c2 = (idx / (T99 * T99)) % 2, b = idx / (2 * T99 * T99);
  float acc = bias[c2];
  const unsigned short* row = p2o + ((size_t)(b * T99 + i) * T99 + j) * 256;
  const float* wr = w + c2 * 256;
  for (int c8 = 0; c8 < 256; c8 += 8) {
    s8v v = *(const s8v*)&row[c8];
#pragma unroll
    for (int q = 0; q < 8; ++q) acc += wr[c8 + q] * bf2f((unsigned short)v[q]);
  }
  cm[idx] = 1.f / (1.f + expf(-acc));
}

// ---------------- host-side encoder driver ----------------
struct EncW {
  const float *qkvw, *qkvb, *ow, *ob, *l1w, *l1b, *l2w, *l2b, *n1g, *n1b, *n2g, *n2b, *nfg, *nfb;
};

// single-stack layer (used for global layers 3..5)
static void enc_layer(float* X, unsigned short* Xb, int ntok, int l,
                      const EncW& W, const unsigned short* Wb,
                      unsigned short* qkvbb, unsigned short* attb, float* yb,
                      int T_, int B_, hipStream_t st) {
  int mg = (ntok + 63) / 64;
  const unsigned short* wq = Wb + (size_t)l * 786432;
  k_gemmb<<<dim3(mg, 12), dim3(256), 0, st>>>(Xb, wq, W.qkvb + l * 768, nullptr, nullptr, qkvbb,
                                              ntok, 768, 256, 4 | 8);
  k_attn<<<dim3(B_ * NHH * T_), dim3(128), 0, st>>>(qkvbb, attb, T_, B_);
  k_gemmb<<<dim3(mg, 4), dim3(256), 0, st>>>(attb, wq + 196608, W.ob + l * 256, X, yb, nullptr,
                                             ntok, 256, 256, 2);
  k_ln<<<dim3(ntok), dim3(256), 0, st>>>(yb, W.n1g + l * 256, W.n1b + l * 256, X, Xb);
  k_gemmb<<<dim3(mg, 16), dim3(256), 0, st>>>(Xb, wq + 262144, W.l1b + l * 1024, nullptr, nullptr, qkvbb,
                                              ntok, 1024, 256, 1 | 4 | 8);
  k_gemmb<<<dim3(mg, 4), dim3(256), 0, st>>>(qkvbb, wq + 524288, W.l2b + l * 256, X, yb, nullptr,
                                             ntok, 256, 1024, 2);
  k_ln<<<dim3(ntok), dim3(256), 0, st>>>(yb, W.n2g + l * 256, W.n2b + l * 256, X, Xb);
}

// ---------------- entry ----------------
extern "C" void kernel_launch(void* const* d_in, const int* in_sizes, int n_in,
                              void* d_out, int out_size, void* d_ws, size_t ws_size,
                              hipStream_t stream) {
  (void)in_sizes; (void)n_in; (void)out_size; (void)ws_size;
  const float* x    = (const float*)d_in[0];
  const float* cbw  = (const float*)d_in[1];
  const float* cbb  = (const float*)d_in[2];
  EncW tg = {(const float*)d_in[3],  (const float*)d_in[4],  (const float*)d_in[5],  (const float*)d_in[6],
             (const float*)d_in[7],  (const float*)d_in[8],  (const float*)d_in[9],  (const float*)d_in[10],
             (const float*)d_in[11], (const float*)d_in[12], (const float*)d_in[13], (const float*)d_in[14],
             (const float*)d_in[15], (const float*)d_in[16]};
  EncW tl = {(const float*)d_in[17], (const float*)d_in[18], (const float*)d_in[19], (const float*)d_in[20],
             (const float*)d_in[21], (const float*)d_in[22], (const float*)d_in[23], (const float*)d_in[24],
             (const float*)d_in[25], (const float*)d_in[26], (const float*)d_in[27], (const float*)d_in[28],
             (const float*)d_in[29], (const float*)d_in[30]};
  const float* s1w = (const float*)d_in[31];
  const float* s1b = (const float*)d_in[32];
  const float* s2w = (const float*)d_in[33];
  const float* s2b = (const float*)d_in[34];
  const float* c3w = (const float*)d_in[35];
  const float* c3b = (const float*)d_in[36];
  const float* p1w = (const float*)d_in[37];
  const float* p1b = (const float*)d_in[38];
  const float* p2w = (const float*)d_in[39];
  const float* p2b = (const float*)d_in[40];
  const float* p3w = (const float*)d_in[41];
  const float* p3b = (const float*)d_in[42];

  float* outp = (float*)d_out; // [cm 39204][start1 198]

  // workspace layout
  char* wp = (char*)d_ws;
  auto alloc = [&](size_t bytes) -> void* {
    void* p = (void*)wp;
    wp += (bytes + 255) & ~(size_t)255;
    return p;
  };
  float* base  = (float*)alloc(sizeof(float) * 2 * CC * T99);
  float* xg    = (float*)alloc(sizeof(float) * T99 * 4 * CC);
  float* xl    = (float*)alloc(sizeof(float) * LSTEP * 6 * CC);
  unsigned short* xgb = (unsigned short*)alloc(sizeof(short) * T99 * 4 * CC);
  unsigned short* xlb = (unsigned short*)alloc(sizeof(short) * LSTEP * 6 * CC);
  unsigned short* qkvbbG = (unsigned short*)alloc(sizeof(short) * 396 * 1024);
  unsigned short* qkvbbL = (unsigned short*)alloc(sizeof(short) * 198 * 1024);
  unsigned short* attbG  = (unsigned short*)alloc(sizeof(short) * 396 * 256);
  unsigned short* attbL  = (unsigned short*)alloc(sizeof(short) * 198 * 256);
  float* ybG   = (float*)alloc(sizeof(float) * 396 * 256);
  float* ybL   = (float*)alloc(sizeof(float) * 198 * 256);
  float* encg  = (float*)alloc(sizeof(float) * T99 * 4 * CC);
  float* encl  = (float*)alloc(sizeof(float) * LSTEP * 6 * CC);
  float* base2 = (float*)alloc(sizeof(float) * 2 * CC * T99);
  float* sbuf  = (float*)alloc(sizeof(float) * 2 * CC * T99);
  float* w3t   = (float*)alloc(sizeof(float) * 32 * 256 * 256);
  unsigned short* Gb = (unsigned short*)alloc(sizeof(short) * (2 * NS_ * T99 * 256 + 512)); // +1KB pad row
  unsigned short* pinb = (unsigned short*)alloc(sizeof(short) * 2 * T99 * T99 * 256);
  unsigned short* p1o  = (unsigned short*)alloc(sizeof(short) * 2 * T99 * T99 * 256);
  unsigned short* p2o  = (unsigned short*)alloc(sizeof(short) * 2 * T99 * T99 * 256);
  unsigned short* wb2a = (unsigned short*)alloc(sizeof(short) * 9 * 256 * 256);
  unsigned short* wb2b = (unsigned short*)alloc(sizeof(short) * 9 * 256 * 256);
  unsigned short* wtgb = (unsigned short*)alloc(sizeof(short) * 6 * 786432);
  unsigned short* wtlb = (unsigned short*)alloc(sizeof(short) * 3 * 786432);

  // 0. weight conversions (independent of everything else)
  k_convW<<<dim3(4096), dim3(256), 0, stream>>>(tg.qkvw, tg.ow, tg.l1w, tg.l2w, 6, wtgb);
  k_convW<<<dim3(2048), dim3(256), 0, stream>>>(tl.qkvw, tl.ow, tl.l1w, tl.l2w, 3, wtlb);
  k_w3t<<<dim3(8192), dim3(256), 0, stream>>>(c3w, w3t);
  k_wb2<<<dim3(288), dim3(256), 0, stream>>>(p1w, wb2a);
  k_wb2<<<dim3(288), dim3(256), 0, stream>>>(p2w, wb2b);
  // 1. conv stem
  k_convbase<<<dim3(512), dim3(128), 0, stream>>>(x, cbw, cbb, base);
  // 2. build encoder inputs
  k_build_xl<<<dim3(198), dim3(256), 0, stream>>>(base, xl, xlb);
  k_build_xg<<<dim3(396), dim3(256), 0, stream>>>(base, xg, xgb);

  // 3. layers 0..2: local || global merged dispatches (M: 198 vs 396; same N,K)
  const int ML = 198, MG = 396;
  const int mgG = 7;
  for (int l = 0; l < 3; ++l) {
    const unsigned short* wqL = wtlb + (size_t)l * 786432;
    const unsigned short* wqG = wtgb + (size_t)l * 786432;
    k_gemmb2<<<dim3(mgG, 12, 2), dim3(256), 0, stream>>>(
        xlb, wqL, tl.qkvb + l * 768, nullptr, nullptr, qkvbbL, ML,
        xgb, wqG, tg.qkvb + l * 768, nullptr, nullptr, qkvbbG, MG, 768, 256, 4 | 8);
    k_attn2<<<dim3(4 * NHH * T99, 1, 2), dim3(128), 0, stream>>>(
        qkvbbL, attbL, LSTEP, 6, qkvbbG, attbG, T99, 4);
    k_gemmb2<<<dim3(mgG, 4, 2), dim3(256), 0, stream>>>(
        attbL, wqL + 196608, tl.ob + l * 256, xl, ybL, nullptr, ML,
        attbG, wqG + 196608, tg.ob + l * 256, xg, ybG, nullptr, MG, 256, 256, 2);
    k_ln2<<<dim3(MG, 1, 2), dim3(256), 0, stream>>>(
        ybL, tl.n1g + l * 256, tl.n1b + l * 256, xl, xlb, ML,
        ybG, tg.n1g + l * 256, tg.n1b + l * 256, xg, xgb, MG);
    k_gemmb2<<<dim3(mgG, 16, 2), dim3(256), 0, stream>>>(
        xlb, wqL + 262144, tl.l1b + l * 1024, nullptr, nullptr, qkvbbL, ML,
        xgb, wqG + 262144, tg.l1b + l * 1024, nullptr, nullptr, qkvbbG, MG, 1024, 256, 1 | 4 | 8);
    k_gemmb2<<<dim3(mgG, 4, 2), dim3(256), 0, stream>>>(
        qkvbbL, wqL + 524288, tl.l2b + l * 256, xl, ybL, nullptr, ML,
        qkvbbG, wqG + 524288, tg.l2b + l * 256, xg, ybG, nullptr, MG, 256, 1024, 2);
    k_ln2<<<dim3(MG, 1, 2), dim3(256), 0, stream>>>(
        ybL, tl.n2g + l * 256, tl.n2b + l * 256, xl, xlb, ML,
        ybG, tg.n2g + l * 256, tg.n2b + l * 256, xg, xgb, MG);
  }
  // 4. global layers 3..5
  for (int l = 3; l < 6; ++l)
    enc_layer(xg, xgb, MG, l, tg, wtgb, qkvbbG, attbG, ybG, T99, 4, stream);
  // 5. final LNs (both stacks) in one dispatch
  k_ln2<<<dim3(MG, 1, 2), dim3(256), 0, stream>>>(
      xl, tl.nfg, tl.nfb, encl, nullptr, ML,
      xg, tg.nfg, tg.nfb, encg, nullptr, MG);
  // 6. combine
  k_combine<<<dim3(198), dim3(256), 0, stream>>>(encl, encg, base2);
  // 7. s-branch -> start1
  k_s1<<<dim3(512), dim3(128), 0, stream>>>(base2, s1w, s1b, sbuf);
  k_s2<<<dim3(198), dim3(256), 0, stream>>>(sbuf, s2w, s2b, outp + 2 * 2 * T99 * T99);
  // 8. fused bm + conv3d
  k_G<<<dim3(4, 32, 2), dim3(256), 0, stream>>>(w3t, base2, Gb);
  k_ppre<<<dim3(T99 * T99), dim3(128), 0, stream>>>(Gb, c3b, (unsigned int*)pinb);
  // 9. p1 conv
  k_conv3x3<<<dim3(169, 2, 2), dim3(256), 0, stream>>>(pinb, wb2a, p1b, p1o);
  // 10. p2 conv
  k_conv3x3<<<dim3(169, 2, 2), dim3(256), 0, stream>>>(p1o, wb2b, p2b, p2o);
  // 11. p3 + sigmoid -> cm
  k_p3<<<dim3(154), dim3(256), 0, stream>>>(p2o, p3w, p3b, outp);
}

// Round 6
// 675.499 us; speedup vs baseline: 1.1246x; 1.1246x over previous
//
#include <hip/hip_runtime.h>
#include <math.h>

// ---------------- constants ----------------
#define T99   99
#define CC    256
#define NHH   8
#define FEAT  400
#define NS_   32
#define LSTEP 33

typedef __attribute__((ext_vector_type(8))) short s8v;   // 8 x bf16 (as raw u16)
typedef __attribute__((ext_vector_type(4))) float f4v;   // MFMA accumulator

// non-volatile: data deps preserve correctness, scheduler may interleave loads
__device__ __forceinline__ void mfma_bf16(f4v& d, s8v a, s8v b) {
  asm("v_mfma_f32_16x16x32_bf16 %0, %1, %2, %0" : "+v"(d) : "v"(a), "v"(b));
}

__device__ __forceinline__ unsigned short f2bf(float f) {
  union { float f; unsigned u; } x; x.f = f;
  unsigned r = x.u + 0x7FFFu + ((x.u >> 16) & 1u);
  return (unsigned short)(r >> 16);
}
__device__ __forceinline__ float bf2f(unsigned short h) {
  union { unsigned u; float f; } x; x.u = ((unsigned)h) << 16;
  return x.f;
}
__device__ __forceinline__ float blo(unsigned u) { union { unsigned x; float f; } c; c.x = u << 16; return c.f; }
__device__ __forceinline__ float bhi(unsigned u) { union { unsigned x; float f; } c; c.x = u & 0xffff0000u; return c.f; }

// sin/cos positional embedding, matches pos_ebb()
__device__ __forceinline__ float pe_val(int pos, int c) {
  int i = c >> 1;
  float freq = expf((float)(2 * i) * (-0.03597789207803197f)); // -ln(10000)/256
  float ang = (float)pos * freq;
  return (c & 1) ? cosf(ang) : sinf(ang);
}

// ---------------- conv stem: grouped conv1d(400->256, k=3, pad=1, g=4) + relu ----------------
__global__ __launch_bounds__(128) void k_convbase(const float* __restrict__ x,
                                                  const float* __restrict__ w,
                                                  const float* __restrict__ bias,
                                                  float* __restrict__ base) {
  int b = blockIdx.x >> 8, co = blockIdx.x & 255, t = threadIdx.x;
  if (t >= T99) return;
  int g = co >> 6;
  float acc = bias[co];
  const float* xp = x + (size_t)(b * FEAT + g * 100) * T99;
  const float* wp = w + (size_t)co * 300;
  for (int ic = 0; ic < 100; ++ic) {
    float x0 = (t > 0)  ? xp[ic * T99 + t - 1] : 0.f;
    float x1 = xp[ic * T99 + t];
    float x2 = (t < 98) ? xp[ic * T99 + t + 1] : 0.f;
    acc += wp[ic * 3] * x0 + wp[ic * 3 + 1] * x1 + wp[ic * 3 + 2] * x2;
  }
  base[(size_t)(b * CC + co) * T99 + t] = fmaxf(acc, 0.f);
}

// ---------------- weight conversion: pack {qkv,o,l1,l2} per layer into bf16 ----------------
__global__ __launch_bounds__(256) void k_convW(const float* __restrict__ qkv, const float* __restrict__ o,
                                               const float* __restrict__ l1, const float* __restrict__ l2,
                                               int L, unsigned short* __restrict__ dst) {
  int total = L * 786432;
  for (int idx = blockIdx.x * 256 + threadIdx.x; idx < total; idx += gridDim.x * 256) {
    int l = idx / 786432, r = idx % 786432;
    float v;
    if (r < 196608)      v = qkv[(size_t)l * 196608 + r];
    else if (r < 262144) v = o[(size_t)l * 65536 + (r - 196608)];
    else if (r < 524288) v = l1[(size_t)l * 262144 + (r - 262144)];
    else                 v = l2[(size_t)l * 262144 + (r - 524288)];
    dst[idx] = f2bf(v);
  }
}

// ---------------- build encoder inputs (fp32 stream + bf16 mirror) ----------------
__global__ __launch_bounds__(256) void k_build_xg(const float* __restrict__ base, float* __restrict__ xg,
                                                  unsigned short* __restrict__ xgb) {
  int idx = blockIdx.x * 256 + threadIdx.x;
  int t = idx >> 10, r = idx & 1023, b4 = r >> 8, c = r & 255;
  float v = (b4 < 2) ? base[(size_t)(b4 * CC + c) * T99 + t]
                     : base[(size_t)((b4 - 2) * CC + c) * T99 + (98 - t)];
  v += pe_val(t, c);
  xg[idx] = v; xgb[idx] = f2bf(v);
}

__global__ __launch_bounds__(256) void k_build_xl(const float* __restrict__ base, float* __restrict__ xl,
                                                  unsigned short* __restrict__ xlb) {
  int idx = blockIdx.x * 256 + threadIdx.x;
  int ls = idx / 1536, r = idx % 1536, j = r >> 8, c = r & 255;
  int g = j >> 1, b = j & 1, t = ls * 3 + g;
  float v = base[(size_t)(b * CC + c) * T99 + t] + pe_val(ls, c);
  xl[idx] = v; xlb[idx] = f2bf(v);
}

// ================= GEMM core (64x64 tile, bf16 MFMA) =================
// flags: 1=relu, 2=residual R, 4=write bf16 Yb, 8=skip fp32 Y
__device__ __forceinline__ void gemm_body(const unsigned short* __restrict__ A,
                                          const unsigned short* __restrict__ W,
                                          const float* __restrict__ bias,
                                          const float* __restrict__ R,
                                          float* __restrict__ Y,
                                          unsigned short* __restrict__ Yb,
                                          int M, int N, int K, int flags,
                                          int m0, int n0) {
  __shared__ __align__(16) unsigned short Al[64][40];
  __shared__ __align__(16) unsigned short Bl[64][40];
  int tid = threadIdx.x;
  int lane = tid & 63, w = tid >> 6, wm = w >> 1, wn = w & 1;
  int sp = tid >> 2, kc = (tid & 3) << 3;
  f4v zero4 = {0.f, 0.f, 0.f, 0.f};
  f4v acc[2][2];
#pragma unroll
  for (int mt = 0; mt < 2; ++mt)
#pragma unroll
    for (int nt = 0; nt < 2; ++nt) acc[mt][nt] = zero4;

  for (int k0 = 0; k0 < K; k0 += 32) {
    s8v av = {0, 0, 0, 0, 0, 0, 0, 0};
    int row = m0 + sp;
    if (row < M) av = *(const s8v*)&A[(size_t)row * K + k0 + kc];
    *(s8v*)&Al[sp][kc] = av;
    *(s8v*)&Bl[sp][kc] = *(const s8v*)&W[(size_t)(n0 + sp) * K + k0 + kc];
    __syncthreads();
    s8v af[2], bf[2];
#pragma unroll
    for (int mt = 0; mt < 2; ++mt)
      af[mt] = *(const s8v*)&Al[wm * 32 + mt * 16 + (lane & 15)][(lane >> 4) * 8];
#pragma unroll
    for (int nt = 0; nt < 2; ++nt)
      bf[nt] = *(const s8v*)&Bl[wn * 32 + nt * 16 + (lane & 15)][(lane >> 4) * 8];
#pragma unroll
    for (int mt = 0; mt < 2; ++mt)
#pragma unroll
      for (int nt = 0; nt < 2; ++nt) mfma_bf16(acc[mt][nt], af[mt], bf[nt]);
    __syncthreads();
  }
  asm volatile("s_nop 7\n\ts_nop 7\n\ts_nop 4");
#pragma unroll
  for (int mt = 0; mt < 2; ++mt) {
#pragma unroll
    for (int nt = 0; nt < 2; ++nt) {
      int col = n0 + wn * 32 + nt * 16 + (lane & 15);
      float bv = bias[col];
#pragma unroll
      for (int r = 0; r < 2 * 2; ++r) {
        int row = m0 + wm * 32 + mt * 16 + (lane >> 4) * 4 + r;
        if (row < M) {
          float v = acc[mt][nt][r] + bv;
          if (flags & 2) v += R[(size_t)row * N + col];
          if (flags & 1) v = fmaxf(v, 0.f);
          if (!(flags & 8)) Y[(size_t)row * N + col] = v;
          if (flags & 4) Yb[(size_t)row * N + col] = f2bf(v);
        }
      }
    }
  }
}

__global__ __launch_bounds__(256) void k_gemmb(const unsigned short* __restrict__ A,
                                               const unsigned short* __restrict__ W,
                                               const float* __restrict__ bias,
                                               const float* __restrict__ R,
                                               float* __restrict__ Y,
                                               unsigned short* __restrict__ Yb,
                                               int M, int N, int K, int flags) {
  gemm_body(A, W, bias, R, Y, Yb, M, N, K, flags, blockIdx.x * 64, blockIdx.y * 64);
}

// dual-job GEMM: z=0 -> job L (local), z=1 -> job G (global). Same N,K,flags.
__global__ __launch_bounds__(256) void k_gemmb2(const unsigned short* __restrict__ A0,
                                                const unsigned short* __restrict__ W0,
                                                const float* __restrict__ bias0,
                                                const float* __restrict__ R0,
                                                float* __restrict__ Y0,
                                                unsigned short* __restrict__ Yb0,
                                                int M0,
                                                const unsigned short* __restrict__ A1,
                                                const unsigned short* __restrict__ W1,
                                                const float* __restrict__ bias1,
                                                const float* __restrict__ R1,
                                                float* __restrict__ Y1,
                                                unsigned short* __restrict__ Yb1,
                                                int M1,
                                                int N, int K, int flags) {
  int m0 = blockIdx.x * 64;
  if (blockIdx.z == 0) {
    if (m0 >= M0) return;
    gemm_body(A0, W0, bias0, R0, Y0, Yb0, M0, N, K, flags, m0, blockIdx.y * 64);
  } else {
    if (m0 >= M1) return;
    gemm_body(A1, W1, bias1, R1, Y1, Yb1, M1, N, K, flags, m0, blockIdx.y * 64);
  }
}

// ---------------- attention: one block per (b,h,q); bf16 in, fp32 math, bf16 out ----------------
__device__ __forceinline__ void attn_body(const unsigned short* __restrict__ qkv,
                                          unsigned short* __restrict__ attb,
                                          int T_, int B_, int bid) {
  __shared__ float qv[32];
  __shared__ float red[128];
  __shared__ float pv[128];
  int tid = threadIdx.x;
  int q = bid % T_;
  int h = (bid / T_) % NHH;
  int b = bid / (T_ * NHH);
  if (tid < 32) qv[tid] = bf2f(qkv[(size_t)(q * B_ + b) * 768 + h * 32 + tid]);
  __syncthreads();
  float s = -1e30f;
  if (tid < T_) {
    const unsigned short* kp = qkv + (size_t)(tid * B_ + b) * 768 + 256 + h * 32;
    float d = 0;
#pragma unroll
    for (int i = 0; i < 32; ++i) d += qv[i] * bf2f(kp[i]);
    s = d * 0.176776695296636881f; // 1/sqrt(32)
  }
  red[tid] = s; __syncthreads();
  for (int o = 64; o > 0; o >>= 1) { if (tid < o) red[tid] = fmaxf(red[tid], red[tid + o]); __syncthreads(); }
  float mx = red[0]; __syncthreads();
  float p = (tid < T_) ? expf(s - mx) : 0.f;
  pv[tid] = p; red[tid] = p; __syncthreads();
  for (int o = 64; o > 0; o >>= 1) { if (tid < o) red[tid] += red[tid + o]; __syncthreads(); }
  float denom = red[0];
  if (tid < 32) {
    float o = 0;
    for (int k = 0; k < T_; ++k) o += pv[k] * bf2f(qkv[(size_t)(k * B_ + b) * 768 + 512 + h * 32 + tid]);
    attb[(size_t)(q * B_ + b) * 256 + h * 32 + tid] = f2bf(o / denom);
  }
}

__global__ __launch_bounds__(128) void k_attn(const unsigned short* __restrict__ qkv,
                                              unsigned short* __restrict__ attb,
                                              int T_, int B_) {
  attn_body(qkv, attb, T_, B_, blockIdx.x);
}

__global__ __launch_bounds__(128) void k_attn2(const unsigned short* __restrict__ qkv0,
                                               unsigned short* __restrict__ attb0, int T0, int B0,
                                               const unsigned short* __restrict__ qkv1,
                                               unsigned short* __restrict__ attb1, int T1, int B1) {
  int bid = blockIdx.x;
  if (blockIdx.z == 0) {
    if (bid >= B0 * NHH * T0) return;
    attn_body(qkv0, attb0, T0, B0, bid);
  } else {
    if (bid >= B1 * NHH * T1) return;
    attn_body(qkv1, attb1, T1, B1, bid);
  }
}

// ---------------- layer norm over C=256; fp32 out + optional bf16 mirror ----------------
__device__ __forceinline__ void ln_body(const float* __restrict__ X, const float* __restrict__ g,
                                        const float* __restrict__ bb, float* __restrict__ Y,
                                        unsigned short* __restrict__ Yb, int tok) {
  __shared__ float rs[256], rq[256];
  int c = threadIdx.x;
  float v = X[(size_t)tok * 256 + c];
  rs[c] = v; rq[c] = v * v; __syncthreads();
  for (int o = 128; o > 0; o >>= 1) { if (c < o) { rs[c] += rs[c + o]; rq[c] += rq[c + o]; } __syncthreads(); }
  float mu = rs[0] * (1.f / 256.f);
  float var = rq[0] * (1.f / 256.f) - mu * mu;
  float r = (v - mu) * rsqrtf(var + 1e-5f) * g[c] + bb[c];
  Y[(size_t)tok * 256 + c] = r;
  if (Yb) Yb[(size_t)tok * 256 + c] = f2bf(r);
}

__global__ __launch_bounds__(256) void k_ln(const float* __restrict__ X, const float* __restrict__ g,
                                            const float* __restrict__ bb, float* __restrict__ Y,
                                            unsigned short* __restrict__ Yb) {
  ln_body(X, g, bb, Y, Yb, blockIdx.x);
}

__global__ __launch_bounds__(256) void k_ln2(const float* __restrict__ X0, const float* __restrict__ g0,
                                             const float* __restrict__ bb0, float* __restrict__ Y0,
                                             unsigned short* __restrict__ Yb0, int n0,
                                             const float* __restrict__ X1, const float* __restrict__ g1,
                                             const float* __restrict__ bb1, float* __restrict__ Y1,
                                             unsigned short* __restrict__ Yb1, int n1) {
  int tok = blockIdx.x;
  if (blockIdx.z == 0) {
    if (tok >= n0) return;
    ln_body(X0, g0, bb0, Y0, Yb0, tok);
  } else {
    if (tok >= n1) return;
    ln_body(X1, g1, bb1, Y1, Yb1, tok);
  }
}

// ---------------- combine: base2 = local + f1 + flip(f2) ----------------
__global__ __launch_bounds__(256) void k_combine(const float* __restrict__ encl, const float* __restrict__ encg,
                                                 float* __restrict__ base2) {
  int idx = blockIdx.x * 256 + threadIdx.x;
  int t = idx % T99, c = (idx / T99) & 255, b = idx / (CC * T99);
  int ls = t / 3, g = t % 3;
  float v = encl[(size_t)(ls * 6 + g * 2 + b) * 256 + c]
          + encg[(size_t)(t * 4 + b) * 256 + c]
          + encg[(size_t)((98 - t) * 4 + 2 + b) * 256 + c];
  base2[idx] = v;
}

// ---------------- s-branch ----------------
__global__ __launch_bounds__(128) void k_s1(const float* __restrict__ base2, const float* __restrict__ w,
                                            const float* __restrict__ bias, float* __restrict__ sbuf) {
  int b = blockIdx.x >> 8, co = blockIdx.x & 255, t = threadIdx.x;
  if (t >= T99) return;
  int g = co >> 6;
  float acc = bias[co];
  const float* xp = base2 + (size_t)(b * CC + g * 64) * T99;
  const float* wp = w + (size_t)co * 192;
  for (int ic = 0; ic < 64; ++ic) {
    float x0 = (t > 0)  ? xp[ic * T99 + t - 1] : 0.f;
    float x1 = xp[ic * T99 + t];
    float x2 = (t < 98) ? xp[ic * T99 + t + 1] : 0.f;
    acc += wp[ic * 3] * x0 + wp[ic * 3 + 1] * x1 + wp[ic * 3 + 2] * x2;
  }
  sbuf[(size_t)(b * CC + co) * T99 + t] = fmaxf(acc, 0.f);
}

__global__ __launch_bounds__(256) void k_s2(const float* __restrict__ sbuf, const float* __restrict__ w,
                                            const float* __restrict__ bias, float* __restrict__ out) {
  __shared__ float rs[256];
  int b = blockIdx.x / T99, t = blockIdx.x % T99, c = threadIdx.x;
  rs[c] = w[c] * sbuf[(size_t)(b * CC + c) * T99 + t];
  __syncthreads();
  for (int o = 128; o > 0; o >>= 1) { if (c < o) rs[c] += rs[c + o]; __syncthreads(); }
  if (c == 0) out[blockIdx.x] = 1.f / (1.f + expf(-(rs[0] + bias[0])));
}

// ---------------- w3 transpose: w3t[n][ci][co] = c3_w[co][ci][n] ----------------
__global__ __launch_bounds__(256) void k_w3t(const float* __restrict__ c3w, float* __restrict__ w3t) {
  int idx = blockIdx.x * 256 + threadIdx.x;
  int co = idx & 255, ci = (idx >> 8) & 255, n = idx >> 16;
  w3t[idx] = c3w[((size_t)(co << 8) + ci) * 32 + n];
}

// ---------------- Gb[n][t][co][b] (bf16, b-interleaved) + zero pad row ----------------
__global__ __launch_bounds__(256) void k_G(const float* __restrict__ w3t, const float* __restrict__ base2,
                                           unsigned short* __restrict__ Gb) {
  int tc = blockIdx.x, n = blockIdx.y, b = blockIdx.z;
  int co = threadIdx.x;
  int t0 = tc * 25;
  float acc[25];
#pragma unroll
  for (int q = 0; q < 25; ++q) acc[q] = 0.f;
  const float* w = w3t + (size_t)n * 65536 + co;
  const float* bs = base2 + (size_t)b * CC * T99 + t0;
  for (int ci = 0; ci < 256; ++ci) {
    float wv = w[(size_t)ci * 256];
#pragma unroll
    for (int q = 0; q < 25; ++q) acc[q] += wv * bs[ci * T99 + q];
  }
#pragma unroll
  for (int q = 0; q < 25; ++q) {
    int t = t0 + q;
    if (t < T99) Gb[((size_t)(n * T99 + t) * 256 + co) * 2 + b] = f2bf(acc[q]);
  }
  // zero the 1-row pad (read by k_ppre's +1024B load with weight 0)
  if (tc == 0 && n == 0 && b == 0)
    ((unsigned int*)(Gb + (size_t)NS_ * T99 * 512))[co] = 0u;
}

// ---------------- p_pre: fused bm-gather + conv3d + relu -> bf16 channel-last ----------------
__global__ __launch_bounds__(128) void k_ppre(const unsigned short* __restrict__ Gb,
                                              const float* __restrict__ c3b,
                                              unsigned int* __restrict__ pinb32) {
  __shared__ float w0s[96], w1s[96];
  __shared__ int   ofs[96];
  int e = blockIdx.x % T99, s = blockIdx.x / T99;
  int tid = threadIdx.x;
  if (s >= e) {
    float z0 = fmaxf(c3b[2 * tid], 0.f), z1 = fmaxf(c3b[2 * tid + 1], 0.f);
    unsigned int zz = ((unsigned)f2bf(z1) << 16) | (unsigned)f2bf(z0);
    pinb32[((size_t)(0 * T99 + s) * T99 + e) * 128 + tid] = zz;
    pinb32[((size_t)(1 * T99 + s) * T99 + e) * 128 + tid] = zz;
    return;
  }
  if (tid < 96) {
    double center = (double)(e - s + 1);
    double S = ((double)s - 0.5 * center) + ((2.0 * center - 1.0) / 95.0) * (double)tid;
    double dn = trunc(S);
    double dec = S - dn;
    int di = (int)dn;
    double uc = ceil(S);
    int ui = (int)uc;
    int n = tid / 3;
    float w0 = 0.f, w1 = 0.f;
    int r0 = 0;
    if (dn >= 0.0 && dn <= 98.0) {
      r0 = di;
      w0 = (float)((1.0 - dec) / 3.0);
      if (uc >= 0.0 && uc <= 98.0) {
        if (ui == di) w0 += (float)(dec / 3.0);
        else          w1  = (float)(dec / 3.0);   // ui == di+1 guaranteed here
      }
    }
    w0s[tid] = w0; w1s[tid] = w1;
    ofs[tid] = (n * T99 + r0) * 1024;  // byte offset of row r0 (256 uints/row)
  }
  __syncthreads();
  float a00 = 0.f, a01 = 0.f, a10 = 0.f, a11 = 0.f; // a[co-sub][b]
  const char* basep = (const char*)Gb + tid * 8;
#pragma unroll 8
  for (int k = 0; k < 96; ++k) {
    float w0 = w0s[k], w1 = w1s[k];
    const uint2* p = (const uint2*)(basep + ofs[k]);
    uint2 u0 = p[0];
    uint2 u1 = p[128];  // +1024 bytes = row r0+1
    a00 += w0 * blo(u0.x) + w1 * blo(u1.x);
    a01 += w0 * bhi(u0.x) + w1 * bhi(u1.x);
    a10 += w0 * blo(u0.y) + w1 * blo(u1.y);
    a11 += w0 * bhi(u0.y) + w1 * bhi(u1.y);
  }
  float b0 = c3b[2 * tid], b1 = c3b[2 * tid + 1];
  unsigned int zb0 = ((unsigned)f2bf(fmaxf(a10 + b1, 0.f)) << 16) | (unsigned)f2bf(fmaxf(a00 + b0, 0.f));
  unsigned int zb1 = ((unsigned)f2bf(fmaxf(a11 + b1, 0.f)) << 16) | (unsigned)f2bf(fmaxf(a01 + b0, 0.f));
  pinb32[((size_t)(0 * T99 + s) * T99 + e) * 128 + tid] = zb0;
  pinb32[((size_t)(1 * T99 + s) * T99 + e) * 128 + tid] = zb1;
}

// ---------------- weight pack for conv3x3: frag-order layout ----------------
// wbf chunk = (tap*8 + kst)*16 + cog; each chunk = 512 halfs = lane*8 (lane: co=cog*16+(lane&15), k=kst*32+(lane>>4)*8)
__global__ __launch_bounds__(256) void k_wb2(const float* __restrict__ pw, unsigned short* __restrict__ wbf) {
  int idx = blockIdx.x * 256 + threadIdx.x;   // 0 .. 73727
  if (idx >= 73728) return;
  int lane = idx & 63;
  int cog  = (idx >> 6) & 15;
  int kst  = (idx >> 10) & 7;
  int tap  = idx >> 13;
  int co = cog * 16 + (lane & 15);
  int k  = kst * 32 + (lane >> 4) * 8;
  s8v v;
#pragma unroll
  for (int j = 0; j < 8; ++j)
    v[j] = (short)f2bf(pw[((size_t)co * 256 + k + j) * 9 + tap]);
  *(s8v*)&wbf[(size_t)idx * 8] = v;
}

// ---------------- const-vector for conv const-region: cout = relu(bias + sum_{tap,ci} W*cin) ----------------
__global__ __launch_bounds__(256) void k_cvec(const float* __restrict__ pw, const float* __restrict__ cin,
                                              const float* __restrict__ bias, int reluCin,
                                              float* __restrict__ coutF, unsigned short* __restrict__ coutB) {
  __shared__ float rs[256];
  int co = blockIdx.x, ci = threadIdx.x;
  float c = cin[ci];
  if (reluCin) c = fmaxf(c, 0.f);
  const float* wp = pw + ((size_t)co * 256 + ci) * 9;
  float wsum = 0.f;
#pragma unroll
  for (int t = 0; t < 9; ++t) wsum += wp[t];
  rs[ci] = wsum * c;
  __syncthreads();
  for (int o = 128; o > 0; o >>= 1) { if (ci < o) rs[ci] += rs[ci + o]; __syncthreads(); }
  if (ci == 0) {
    float r = fmaxf(bias[co] + rs[0], 0.f);
    coutF[co] = r;
    coutB[co] = f2bf(r);
  }
}

// ---------------- 3x3 conv: halo-LDS, software-pipelined MFMA, const-region skip ----------------
// block: 8x8 spatial tile, 128 co, one b. 4 waves (2 sp x 2 co), wave = 32sp x 64co.
__device__ __forceinline__ int aoff(int s) {   // halfs offset into halo for step s
  int tap = s >> 3, kst = s & 7;
  return ((tap / 3) * 10 + (tap % 3)) * 264 + kst * 32;
}
__device__ __forceinline__ void ldb4(const unsigned short* __restrict__ B0, int s, s8v* dst) {
#pragma unroll
  for (int nt = 0; nt < 4; ++nt) dst[nt] = *(const s8v*)(B0 + (size_t)s * 8192 + nt * 512);
}

__global__ __launch_bounds__(256) void k_conv3x3(const unsigned short* __restrict__ in,
                                                 const unsigned short* __restrict__ wbf,
                                                 const float* __restrict__ bias,
                                                 const unsigned short* __restrict__ cvecB,
                                                 int D, int lo, int hi,
                                                 unsigned short* __restrict__ out) {
  __shared__ __align__(16) unsigned short Ah[100 * 264];
  int b = blockIdx.z;
  int co0 = blockIdx.y * 128;
  int ti = blockIdx.x / 13, tj = blockIdx.x % 13;
  int i0 = ti * 8, j0 = tj * 8;
  int tid = threadIdx.x;

  // const-region tile: whole 10x10 halo inside the constant field -> output = cvec
  if (i0 - 1 >= lo && i0 + 8 <= hi && j0 - 1 >= lo && j0 + 8 <= hi && i0 - 1 >= j0 + 8 + D) {
    const unsigned int* cv = (const unsigned int*)(cvecB + co0);
    unsigned int* ob = (unsigned int*)out;
#pragma unroll
    for (int r = 0; r < 16; ++r) {
      int idx = r * 256 + tid;
      int sp = idx >> 6, cp = idx & 63;
      int gi = i0 + (sp >> 3), gj = j0 + (sp & 7);
      ob[((size_t)(b * T99 + gi) * T99 + gj) * 128 + (co0 >> 1) + cp] = cv[cp];
    }
    return;
  }

  // stage halo once: 100 rows x 256 ch
#pragma unroll
  for (int it = 0; it < 13; ++it) {
    int chunk = it * 256 + tid;
    if (chunk < 3200) {
      int row = chunk >> 5;
      int cc = (chunk & 31) * 8;
      int gi = i0 + row / 10 - 1, gj = j0 + row % 10 - 1;
      s8v val = {0, 0, 0, 0, 0, 0, 0, 0};
      if (gi >= 0 && gi < T99 && gj >= 0 && gj < T99)
        val = *(const s8v*)&in[((size_t)(b * T99 + gi) * T99 + gj) * 256 + cc];
      *(s8v*)&Ah[row * 264 + cc] = val;
    }
  }
  __syncthreads();

  int lane = tid & 63, w = tid >> 6, wm = w >> 1, wn = w & 1;
  int l15 = lane & 15, lk = lane >> 4;
  int spL0 = wm * 32 + l15, spL1 = spL0 + 16;
  int hr0 = (spL0 >> 3) * 10 + (spL0 & 7);   // base (no center offset; aoff supplies it)
  int hr1 = (spL1 >> 3) * 10 + (spL1 & 7);
  const unsigned short* A0 = &Ah[hr0 * 264 + lk * 8];
  const unsigned short* A1 = &Ah[hr1 * 264 + lk * 8];
  int cogbase = blockIdx.y * 8 + wn * 4;
  const unsigned short* B0 = wbf + (size_t)cogbase * 512 + (size_t)lane * 8;

  f4v acc[2][4];
#pragma unroll
  for (int mt = 0; mt < 2; ++mt)
#pragma unroll
    for (int nt = 0; nt < 4; ++nt) acc[mt][nt] = (f4v){0.f, 0.f, 0.f, 0.f};

  // software pipeline: B 2 ahead, A 1 ahead
  s8v a0c, a1c, a0n, a1n;
  s8v bq[3][4];
  a0c = *(const s8v*)(A0 + aoff(0));
  a1c = *(const s8v*)(A1 + aoff(0));
  a0n = a0c; a1n = a1c;
  ldb4(B0, 0, bq[0]);
  ldb4(B0, 1, bq[1]);
#pragma unroll
  for (int s = 0; s < 72; ++s) {
    if (s + 2 < 72) ldb4(B0, s + 2, bq[(s + 2) % 3]);
    if (s + 1 < 72) {
      a0n = *(const s8v*)(A0 + aoff(s + 1));
      a1n = *(const s8v*)(A1 + aoff(s + 1));
    }
#pragma unroll
    for (int nt = 0; nt < 4; ++nt) {
      mfma_bf16(acc[0][nt], a0c, bq[s % 3][nt]);
      mfma_bf16(acc[1][nt], a1c, bq[s % 3][nt]);
    }
    a0c = a0n; a1c = a1n;
  }

  asm volatile("s_nop 7\n\ts_nop 7\n\ts_nop 4");
#pragma unroll
  for (int mt = 0; mt < 2; ++mt) {
#pragma unroll
    for (int nt = 0; nt < 4; ++nt) {
      int co = co0 + wn * 64 + nt * 16 + l15;
      float bv = bias[co];
#pragma unroll
      for (int r = 0; r < 4; ++r) {
        int sp = wm * 32 + mt * 16 + lk * 4 + r;
        int gi = i0 + (sp >> 3), gj = j0 + (sp & 7);
        if (gi < T99 && gj < T99) {
          float v = fmaxf(acc[mt][nt][r] + bv, 0.f);
          out[((size_t)(b * T99 + gi) * T99 + gj) * 256 + co] = f2bf(v);
        }
      }
    }
  }
}

// ---------------- p3 1x1 conv (256->2) + sigmoid -> cm ----------------
__global__ __launch_bounds__(256) void k_p3(const unsigned short* __restrict__ p2o,
                                            const float* __restrict__ w, const float* __restrict__ bias,
                                            float* __restrict__ cm) {
  int idx = blockIdx.x * 256 + threadIdx.x;
  if (idx >= 2 * 2 * T99 * T99) return;
  int j = idx % T99, i = (idx / T99) % T99, c2 = (idx / (T99 * T99)) % 2, b = idx / (2 * T99 * T99);
  float acc = bias[c2];
  const unsigned short* row = p2o + ((size_t)(b * T99 + i) * T99 + j) * 256;
  const float* wr = w + c2 * 256;
  for (int c8 = 0; c8 < 256; c8 += 8) {
    s8v v = *(const s8v*)&row[c8];
#pragma unroll
    for (int q = 0; q < 8; ++q) acc += wr[c8 + q] * bf2f((unsigned short)v[q]);
  }
  cm[idx] = 1.f / (1.f + expf(-acc));
}

// ---------------- host-side encoder driver ----------------
struct EncW {
  const float *qkvw, *qkvb, *ow, *ob, *l1w, *l1b, *l2w, *l2b, *n1g, *n1b, *n2g, *n2b, *nfg, *nfb;
};

static void enc_layer(float* X, unsigned short* Xb, int ntok, int l,
                      const EncW& W, const unsigned short* Wb,
                      unsigned short* qkvbb, unsigned short* attb, float* yb,
                      int T_, int B_, hipStream_t st) {
  int mg = (ntok + 63) / 64;
  const unsigned short* wq = Wb + (size_t)l * 786432;
  k_gemmb<<<dim3(mg, 12), dim3(256), 0, st>>>(Xb, wq, W.qkvb + l * 768, nullptr, nullptr, qkvbb,
                                              ntok, 768, 256, 4 | 8);
  k_attn<<<dim3(B_ * NHH * T_), dim3(128), 0, st>>>(qkvbb, attb, T_, B_);
  k_gemmb<<<dim3(mg, 4), dim3(256), 0, st>>>(attb, wq + 196608, W.ob + l * 256, X, yb, nullptr,
                                             ntok, 256, 256, 2);
  k_ln<<<dim3(ntok), dim3(256), 0, st>>>(yb, W.n1g + l * 256, W.n1b + l * 256, X, Xb);
  k_gemmb<<<dim3(mg, 16), dim3(256), 0, st>>>(Xb, wq + 262144, W.l1b + l * 1024, nullptr, nullptr, qkvbb,
                                              ntok, 1024, 256, 1 | 4 | 8);
  k_gemmb<<<dim3(mg, 4), dim3(256), 0, st>>>(qkvbb, wq + 524288, W.l2b + l * 256, X, yb, nullptr,
                                             ntok, 256, 1024, 2);
  k_ln<<<dim3(ntok), dim3(256), 0, st>>>(yb, W.n2g + l * 256, W.n2b + l * 256, X, Xb);
}

// ---------------- entry ----------------
extern "C" void kernel_launch(void* const* d_in, const int* in_sizes, int n_in,
                              void* d_out, int out_size, void* d_ws, size_t ws_size,
                              hipStream_t stream) {
  (void)in_sizes; (void)n_in; (void)out_size; (void)ws_size;
  const float* x    = (const float*)d_in[0];
  const float* cbw  = (const float*)d_in[1];
  const float* cbb  = (const float*)d_in[2];
  EncW tg = {(const float*)d_in[3],  (const float*)d_in[4],  (const float*)d_in[5],  (const float*)d_in[6],
             (const float*)d_in[7],  (const float*)d_in[8],  (const float*)d_in[9],  (const float*)d_in[10],
             (const float*)d_in[11], (const float*)d_in[12], (const float*)d_in[13], (const float*)d_in[14],
             (const float*)d_in[15], (const float*)d_in[16]};
  EncW tl = {(const float*)d_in[17], (const float*)d_in[18], (const float*)d_in[19], (const float*)d_in[20],
             (const float*)d_in[21], (const float*)d_in[22], (const float*)d_in[23], (const float*)d_in[24],
             (const float*)d_in[25], (const float*)d_in[26], (const float*)d_in[27], (const float*)d_in[28],
             (const float*)d_in[29], (const float*)d_in[30]};
  const float* s1w = (const float*)d_in[31];
  const float* s1b = (const float*)d_in[32];
  const float* s2w = (const float*)d_in[33];
  const float* s2b = (const float*)d_in[34];
  const float* c3w = (const float*)d_in[35];
  const float* c3b = (const float*)d_in[36];
  const float* p1w = (const float*)d_in[37];
  const float* p1b = (const float*)d_in[38];
  const float* p2w = (const float*)d_in[39];
  const float* p2b = (const float*)d_in[40];
  const float* p3w = (const float*)d_in[41];
  const float* p3b = (const float*)d_in[42];

  float* outp = (float*)d_out; // [cm 39204][start1 198]

  // workspace layout
  char* wp = (char*)d_ws;
  auto alloc = [&](size_t bytes) -> void* {
    void* p = (void*)wp;
    wp += (bytes + 255) & ~(size_t)255;
    return p;
  };
  float* base  = (float*)alloc(sizeof(float) * 2 * CC * T99);
  float* xg    = (float*)alloc(sizeof(float) * T99 * 4 * CC);
  float* xl    = (float*)alloc(sizeof(float) * LSTEP * 6 * CC);
  unsigned short* xgb = (unsigned short*)alloc(sizeof(short) * T99 * 4 * CC);
  unsigned short* xlb = (unsigned short*)alloc(sizeof(short) * LSTEP * 6 * CC);
  unsigned short* qkvbbG = (unsigned short*)alloc(sizeof(short) * 396 * 1024);
  unsigned short* qkvbbL = (unsigned short*)alloc(sizeof(short) * 198 * 1024);
  unsigned short* attbG  = (unsigned short*)alloc(sizeof(short) * 396 * 256);
  unsigned short* attbL  = (unsigned short*)alloc(sizeof(short) * 198 * 256);
  float* ybG   = (float*)alloc(sizeof(float) * 396 * 256);
  float* ybL   = (float*)alloc(sizeof(float) * 198 * 256);
  float* encg  = (float*)alloc(sizeof(float) * T99 * 4 * CC);
  float* encl  = (float*)alloc(sizeof(float) * LSTEP * 6 * CC);
  float* base2 = (float*)alloc(sizeof(float) * 2 * CC * T99);
  float* sbuf  = (float*)alloc(sizeof(float) * 2 * CC * T99);
  float* w3t   = (float*)alloc(sizeof(float) * 32 * 256 * 256);
  unsigned short* Gb = (unsigned short*)alloc(sizeof(short) * (2 * NS_ * T99 * 256 + 512)); // +1KB pad row
  unsigned short* pinb = (unsigned short*)alloc(sizeof(short) * 2 * T99 * T99 * 256);
  unsigned short* p1o  = (unsigned short*)alloc(sizeof(short) * 2 * T99 * T99 * 256);
  unsigned short* p2o  = (unsigned short*)alloc(sizeof(short) * 2 * T99 * T99 * 256);
  unsigned short* wb2a = (unsigned short*)alloc(sizeof(short) * 9 * 256 * 256);
  unsigned short* wb2b = (unsigned short*)alloc(sizeof(short) * 9 * 256 * 256);
  unsigned short* wtgb = (unsigned short*)alloc(sizeof(short) * 6 * 786432);
  unsigned short* wtlb = (unsigned short*)alloc(sizeof(short) * 3 * 786432);
  float* c1F = (float*)alloc(sizeof(float) * 256);
  unsigned short* c1B = (unsigned short*)alloc(sizeof(short) * 256);
  float* c2F = (float*)alloc(sizeof(float) * 256);
  unsigned short* c2B = (unsigned short*)alloc(sizeof(short) * 256);

  // 0. weight conversions + const vectors (independent preamble)
  k_convW<<<dim3(4096), dim3(256), 0, stream>>>(tg.qkvw, tg.ow, tg.l1w, tg.l2w, 6, wtgb);
  k_convW<<<dim3(2048), dim3(256), 0, stream>>>(tl.qkvw, tl.ow, tl.l1w, tl.l2w, 3, wtlb);
  k_w3t<<<dim3(8192), dim3(256), 0, stream>>>(c3w, w3t);
  k_wb2<<<dim3(288), dim3(256), 0, stream>>>(p1w, wb2a);
  k_wb2<<<dim3(288), dim3(256), 0, stream>>>(p2w, wb2b);
  k_cvec<<<dim3(256), dim3(256), 0, stream>>>(p1w, c3b, p1b, 1, c1F, c1B);
  k_cvec<<<dim3(256), dim3(256), 0, stream>>>(p2w, c1F, p2b, 0, c2F, c2B);
  // 1. conv stem
  k_convbase<<<dim3(512), dim3(128), 0, stream>>>(x, cbw, cbb, base);
  // 2. build encoder inputs
  k_build_xl<<<dim3(198), dim3(256), 0, stream>>>(base, xl, xlb);
  k_build_xg<<<dim3(396), dim3(256), 0, stream>>>(base, xg, xgb);

  // 3. layers 0..2: local || global merged dispatches
  const int ML = 198, MG = 396;
  const int mgG = 7;
  for (int l = 0; l < 3; ++l) {
    const unsigned short* wqL = wtlb + (size_t)l * 786432;
    const unsigned short* wqG = wtgb + (size_t)l * 786432;
    k_gemmb2<<<dim3(mgG, 12, 2), dim3(256), 0, stream>>>(
        xlb, wqL, tl.qkvb + l * 768, nullptr, nullptr, qkvbbL, ML,
        xgb, wqG, tg.qkvb + l * 768, nullptr, nullptr, qkvbbG, MG, 768, 256, 4 | 8);
    k_attn2<<<dim3(4 * NHH * T99, 1, 2), dim3(128), 0, stream>>>(
        qkvbbL, attbL, LSTEP, 6, qkvbbG, attbG, T99, 4);
    k_gemmb2<<<dim3(mgG, 4, 2), dim3(256), 0, stream>>>(
        attbL, wqL + 196608, tl.ob + l * 256, xl, ybL, nullptr, ML,
        attbG, wqG + 196608, tg.ob + l * 256, xg, ybG, nullptr, MG, 256, 256, 2);
    k_ln2<<<dim3(MG, 1, 2), dim3(256), 0, stream>>>(
        ybL, tl.n1g + l * 256, tl.n1b + l * 256, xl, xlb, ML,
        ybG, tg.n1g + l * 256, tg.n1b + l * 256, xg, xgb, MG);
    k_gemmb2<<<dim3(mgG, 16, 2), dim3(256), 0, stream>>>(
        xlb, wqL + 262144, tl.l1b + l * 1024, nullptr, nullptr, qkvbbL, ML,
        xgb, wqG + 262144, tg.l1b + l * 1024, nullptr, nullptr, qkvbbG, MG, 1024, 256, 1 | 4 | 8);
    k_gemmb2<<<dim3(mgG, 4, 2), dim3(256), 0, stream>>>(
        qkvbbL, wqL + 524288, tl.l2b + l * 256, xl, ybL, nullptr, ML,
        qkvbbG, wqG + 524288, tg.l2b + l * 256, xg, ybG, nullptr, MG, 256, 1024, 2);
    k_ln2<<<dim3(MG, 1, 2), dim3(256), 0, stream>>>(
        ybL, tl.n2g + l * 256, tl.n2b + l * 256, xl, xlb, ML,
        ybG, tg.n2g + l * 256, tg.n2b + l * 256, xg, xgb, MG);
  }
  // 4. global layers 3..5
  for (int l = 3; l < 6; ++l)
    enc_layer(xg, xgb, MG, l, tg, wtgb, qkvbbG, attbG, ybG, T99, 4, stream);
  // 5. final LNs
  k_ln2<<<dim3(MG, 1, 2), dim3(256), 0, stream>>>(
      xl, tl.nfg, tl.nfb, encl, nullptr, ML,
      xg, tg.nfg, tg.nfb, encg, nullptr, MG);
  // 6. combine
  k_combine<<<dim3(198), dim3(256), 0, stream>>>(encl, encg, base2);
  // 7. s-branch -> start1
  k_s1<<<dim3(512), dim3(128), 0, stream>>>(base2, s1w, s1b, sbuf);
  k_s2<<<dim3(198), dim3(256), 0, stream>>>(sbuf, s2w, s2b, outp + 2 * 2 * T99 * T99);
  // 8. fused bm + conv3d
  k_G<<<dim3(4, 32, 2), dim3(256), 0, stream>>>(w3t, base2, Gb);
  k_ppre<<<dim3(T99 * T99), dim3(128), 0, stream>>>(Gb, c3b, (unsigned int*)pinb);
  // 9. p1 conv  (const field: pinb const where i>=j, box [0,98])
  k_conv3x3<<<dim3(169, 2, 2), dim3(256), 0, stream>>>(pinb, wb2a, p1b, c1B, 0, 0, 98, p1o);
  // 10. p2 conv (const field: p1o == c1 where i>=j+2, box [1,97])
  k_conv3x3<<<dim3(169, 2, 2), dim3(256), 0, stream>>>(p1o, wb2b, p2b, c2B, 2, 1, 97, p2o);
  // 11. p3 + sigmoid -> cm
  k_p3<<<dim3(154), dim3(256), 0, stream>>>(p2o, p3w, p3b, outp);
}